// Round 15
// baseline (247.059 us; speedup 1.0000x reference)
//
#include <hip/hip_runtime.h>
#include <cstdint>

#define KNB 16
#define FDIM 64
#define HDIM 128
#define NPB 8           // nodes per egcn block
#define ROWS 128        // edge rows per egcn block
#define CMAXW 80        // candidates per lane (segments up to 5120)
#define PADN 5120       // c4 padding entries

typedef unsigned long long ull;
typedef _Float16 f16x8 __attribute__((ext_vector_type(8)));
typedef float    f32x16 __attribute__((ext_vector_type(16)));

__device__ __forceinline__ float selu_f(float x){
    const float a = 1.6732632423543772f, s = 1.0507009873554805f;
    return x > 0.f ? s * x : s * a * (__expf(x) - 1.0f);
}

__device__ __forceinline__ unsigned int pack2(float a, float b){
    union { _Float16 h[2]; unsigned int u; } t;
    t.h[0] = (_Float16)a; t.h[1] = (_Float16)b;
    return t.u;
}

__device__ __forceinline__ f16x8 ldfrag4(const unsigned int* p, unsigned int di){
    union { uint4 q; f16x8 v; } t;
    t.q = *(const uint4*)(p + di);
    return t.v;
}

__device__ __forceinline__ f16x8 ldg8h(const _Float16* p){
    union { uint4 q; f16x8 v; } t;
    t.q = *(const uint4*)p;
    return t.v;
}

// ---- u32 min-reduce across a wave64 in pure-VALU DPP ----
template<int CTRL>
__device__ __forceinline__ unsigned int dppmin_u32(unsigned int v){
    unsigned int t = (unsigned int)__builtin_amdgcn_update_dpp(
        -1, (int)v, CTRL, 0xF, 0xF, false);
    return t < v ? t : v;
}
__device__ __forceinline__ unsigned int wave_min_u32(unsigned int v){
    v = dppmin_u32<0x111>(v);
    v = dppmin_u32<0x112>(v);
    v = dppmin_u32<0x114>(v);
    v = dppmin_u32<0x118>(v);
    v = dppmin_u32<0x142>(v);
    v = dppmin_u32<0x143>(v);
    return (unsigned int)__builtin_amdgcn_readlane((int)v, 63);
}

#define SWZ(row, d) ((unsigned int)(d) ^ ((((unsigned int)(row)) & 7u) << 2))

// ---------------------------------------------------------------------------
// Kernel 0: fused prep.
//  b in [0,192):   WT[n][k]   = W_e*[k][n] fp16 (3 x 128x128)
//  b in [192,288): WN1T[n][k] = W_n1[k][n] fp16 (128x192)
//  b in [288,352): WN2T[n][k] = W_n2[k][n] fp16 (128x128)
//  b >= 352:       c4[j] = {x,y,z,nrm}; pad = {0,0,0,+inf}
// ---------------------------------------------------------------------------
__global__ __launch_bounds__(256) void prep_kernel(
    const float* __restrict__ We1, const float* __restrict__ We2,
    const float* __restrict__ Wc1, _Float16* __restrict__ WT,
    const float* __restrict__ Wn1, _Float16* __restrict__ WN1T,
    const float* __restrict__ Wn2, _Float16* __restrict__ WN2T,
    const float* __restrict__ coords, float4* __restrict__ c4, int n, int npad)
{
    int b = blockIdx.x;
    if (b < 192){
        int id = b * 256 + threadIdx.x;
        int m  = id >> 14;
        int r  = id & 16383;
        int nn = (r >> 7) & 127;
        int k  = r & 127;
        float v;
        if (m == 0)      v = We1[(k + 1) * 128 + nn];
        else if (m == 1) v = We2[k * 128 + nn];
        else             v = Wc1[k * 128 + nn];
        WT[m * 16384 + nn * 128 + k] = (_Float16)v;
    } else if (b < 288){
        int id = (b - 192) * 256 + threadIdx.x;   // 0..24575
        int nn = id / 192, k = id - nn * 192;
        WN1T[nn * 192 + k] = (_Float16)Wn1[k * 128 + nn];
    } else if (b < 352){
        int id = (b - 288) * 256 + threadIdx.x;   // 0..16383
        int nn = id >> 7, k = id & 127;
        WN2T[nn * 128 + k] = (_Float16)Wn2[k * 128 + nn];
    } else {
        int i = (b - 352) * 256 + threadIdx.x;
        if (i < n){
            float x = coords[3*i], y = coords[3*i+1], z = coords[3*i+2];
            float nrm = __fadd_rn(__fadd_rn(__fmul_rn(x,x), __fmul_rn(y,y)), __fmul_rn(z,z));
            c4[i] = make_float4(x, y, z, nrm);
        } else if (i < npad){
            c4[i] = make_float4(0.f, 0.f, 0.f, __uint_as_float(0x7f800000u));
        }
    }
}

// ---------------------------------------------------------------------------
// Kernel 1: exact KNN, one wave per block (grid = n). R14 post-mortem:
// VGPR_Count=32 means the declared 8-wide load batch never had >2 loads in
// flight (compiler collapsed it to fit 32 regs) -> 52% VALUBusy = vmcnt
// stalls. This round: __launch_bounds__(64,4) (128-VGPR budget) + MANUAL
// double-buffered load pipeline (batch k+1 loads issue before batch k's
// insert chain runs). Extraction/refill/d2 math bit-identical to R12/R14.
// ---------------------------------------------------------------------------
__global__ __launch_bounds__(64, 4) void knn_kernel(
    const float4* __restrict__ c4,
    const int* __restrict__ row_splits, int nseg, int n,
    int* __restrict__ nidx, float* __restrict__ ndist, int* __restrict__ idx0,
    float* __restrict__ out_nidx, float* __restrict__ out_d)
{
    const int lane = threadIdx.x;
    const int i    = blockIdx.x;
    if (i >= n) return;

    int lo = 0, hi = n;
    for (int s = 0; s < nseg; ++s){
        int a = row_splits[s], b = row_splits[s+1];
        if (i >= a && i < b){ lo = a; hi = b; }
    }

    const float4 ci = c4[i];
    const float cx = ci.x, cy = ci.y, cz = ci.z, nrmi = ci.w;

    const int jbase = lo + lane;
    const float FINF = __uint_as_float(0x7f800000u);

    ull m1 = ~0ull, m2 = ~0ull, m3 = ~0ull;

    #define D2_OF(v) __fsub_rn(__fadd_rn(nrmi, (v).w), __fmul_rn(2.0f, \
        __fadd_rn(__fadd_rn(__fmul_rn(cx,(v).x), __fmul_rn(cy,(v).y)), __fmul_rn(cz,(v).z))))
    #define INS(kk) { \
        ull n1 = (kk) < m1 ? (kk) : m1; \
        ull t1 = (kk) < m1 ? m1 : (kk); \
        ull n2 = t1 < m2 ? t1 : m2; \
        ull t2 = t1 < m2 ? m2 : t1; \
        ull n3 = t2 < m3 ? t2 : m3; \
        m1 = n1; m2 = n2; m3 = n3; }

    // ---- software-pipelined pass 1: batch k+1 in flight during batch k ----
    float4 cur[8], nxt[8];
    #pragma unroll
    for (int q = 0; q < 8; ++q) cur[q] = c4[jbase + q*64];

    for (int c0 = 0; c0 < CMAXW; c0 += 8){
        if (c0 + 8 < CMAXW){
            #pragma unroll
            for (int q = 0; q < 8; ++q) nxt[q] = c4[jbase + (c0 + 8 + q)*64];
        }
        #pragma unroll
        for (int q = 0; q < 8; ++q){
            int j = jbase + (c0 + q)*64;
            float dv = (j < hi) ? fmaxf(D2_OF(cur[q]), 0.0f) : FINF;
            ull kk = (((ull)__float_as_uint(dv)) << 32) | (unsigned int)j;
            INS(kk)
        }
        #pragma unroll
        for (int q = 0; q < 8; ++q) cur[q] = nxt[q];
    }
    int vcnt = 3;

    for (int r = 0; r < KNB + 1; ++r){
        unsigned int h32 = (unsigned int)(m1 >> 32);
        unsigned int l32 = (unsigned int)m1;
        unsigned int wmd = wave_min_u32(h32);
        unsigned int jm  = (h32 == wmd) ? l32 : 0xFFFFFFFFu;
        unsigned int wmj = wave_min_u32(jm);

        bool own = (h32 == wmd) && (l32 == wmj);
        bool need = false;
        if (own){
            int   j  = (int)wmj;
            float dv = __uint_as_float(wmd);
            if (r == 0){
                idx0[i] = j;
            } else {
                int rr = r - 1;
                nidx[i*KNB + rr]     = j;
                ndist[i*KNB + rr]    = dv;
                out_nidx[i*KNB + rr] = (float)j;
                out_d[i*KNB + rr]    = dv;
            }
            m1 = m2; m2 = m3; m3 = ~0ull;
            need = (--vcnt == 0);
        }

        if (__ballot((int)need)){   // wave-uniform: body never issues if untaken
            if (need){
                ull b = (((ull)wmd) << 32) | wmj;
                m1 = m2 = m3 = ~0ull;
                for (int c = 0; c < CMAXW; ++c){
                    int j = jbase + c*64;
                    float4 v = c4[j];
                    float dv = (j < hi) ? fmaxf(D2_OF(v), 0.0f) : FINF;
                    ull kk = (((ull)__float_as_uint(dv)) << 32) | (unsigned int)j;
                    kk = kk > b ? kk : ~0ull;
                    INS(kk)
                }
                vcnt = 3;
            }
        }
    }
    #undef INS
    #undef D2_OF
}

// ---------------------------------------------------------------------------
// Kernel 2: egcn, R10 structure (LDS wt staging, XOR swizzle, (256,2) — the
// no-spill config). aggbuf written as fp16 for the MFMA node MLP.
// (unchanged this round)
// ---------------------------------------------------------------------------
__global__ __launch_bounds__(256, 2) void egcn_node_kernel(
    const float* __restrict__ h, const float* __restrict__ coords,
    const int* __restrict__ nidx, const float* __restrict__ ndist,
    const int* __restrict__ idx0, const _Float16* __restrict__ WTg,
    const float* __restrict__ W_e1, const float* __restrict__ b_e1,
    const float* __restrict__ b_e2, const float* __restrict__ b_c1,
    const float* __restrict__ W_c2, const float* __restrict__ b_c2,
    unsigned int* __restrict__ aggout, float* __restrict__ out_coords, int n)
{
    __shared__ __attribute__((aligned(16))) _Float16 Act[ROWS * 128];   // 32768 B
    __shared__ __attribute__((aligned(16))) unsigned int wt[ROWS * 64]; // 32768 B
    __shared__ float agg[NPB][HDIM];                                    // 4096 B
    __shared__ float dls[ROWS];
    __shared__ int   nb[ROWS];
    __shared__ int   j0s[NPB];
    __shared__ float wedge[ROWS];

    const int g0  = blockIdx.x * NPB;
    const int tid = threadIdx.x;
    const int lane = tid & 63, wid = tid >> 6;
    const int ln31 = lane & 31, grp = lane >> 5;
    const int rt  = wid;                 // row tile 0..3 (32 edge rows each)

    if (tid < ROWS){
        int e = min(g0*KNB + tid, n*KNB - 1);
        nb[tid]  = nidx[e];
        dls[tid] = ndist[e];
    }
    if (tid < NPB) j0s[tid] = idx0[min(g0 + tid, n - 1)];
    __syncthreads();

    unsigned int* actd = (unsigned int*)Act;

    // ---- stage Act = [h_self | h_neig] fp16, float4 loads + swizzled b128 ----
    {
        int r = tid >> 1, half = tid & 1;
        const float4* hs = (const float4*)(h + (size_t)j0s[r >> 4] * FDIM + half*32);
        const float4* hn = (const float4*)(h + (size_t)nb[r] * FDIM + half*32);
        unsigned int rb = (unsigned int)r * 64;
        uint4 buf[4];
        #pragma unroll
        for (int q = 0; q < 4; ++q){
            float4 a = hs[2*q], b = hs[2*q+1];
            buf[q].x = pack2(a.x,a.y); buf[q].y = pack2(a.z,a.w);
            buf[q].z = pack2(b.x,b.y); buf[q].w = pack2(b.z,b.w);
        }
        #pragma unroll
        for (int q = 0; q < 4; ++q)
            *(uint4*)(actd + rb + SWZ(r, half*16 + 4*q)) = buf[q];
        #pragma unroll
        for (int q = 0; q < 4; ++q){
            float4 a = hn[2*q], b = hn[2*q+1];
            buf[q].x = pack2(a.x,a.y); buf[q].y = pack2(a.z,a.w);
            buf[q].z = pack2(b.x,b.y); buf[q].w = pack2(b.z,b.w);
        }
        #pragma unroll
        for (int q = 0; q < 4; ++q)
            *(uint4*)(actd + rb + SWZ(r, 32 + half*16 + 4*q)) = buf[q];
    }
    auto stage_wt = [&](const _Float16* Wg){
        int nr = tid >> 1, half = tid & 1;
        const uint4* src = (const uint4*)(Wg + nr * 128 + half*64);
        unsigned int rb = (unsigned int)nr * 64;
        #pragma unroll
        for (int q = 0; q < 8; ++q)
            *(uint4*)(wt + rb + SWZ(nr, half*32 + q*4)) = src[q];
    };
    stage_wt(WTg);
    __syncthreads();

    const unsigned int sA    = ((unsigned int)ln31 & 7u) << 2;
    const unsigned int aRow  = (unsigned int)(rt*32 + ln31) * 64;
    const unsigned int bRow0 = (unsigned int)(ln31      ) * 64;
    const unsigned int bRow1 = (unsigned int)(32  + ln31) * 64;
    const unsigned int bRow2 = (unsigned int)(64  + ln31) * 64;
    const unsigned int bRow3 = (unsigned int)(96  + ln31) * 64;

    auto gemm4 = [&](f32x16& A0, f32x16& A1, f32x16& A2, f32x16& A3){
        #pragma unroll
        for (int ks = 0; ks < 8; ++ks){
            const unsigned int o = ((unsigned int)(ks*8 + grp*4)) ^ sA;
            f16x8 af = ldfrag4(actd, aRow + o);
            A0 = __builtin_amdgcn_mfma_f32_32x32x16_f16(af, ldfrag4(wt, bRow0 + o), A0, 0, 0, 0);
            A1 = __builtin_amdgcn_mfma_f32_32x32x16_f16(af, ldfrag4(wt, bRow1 + o), A1, 0, 0, 0);
            A2 = __builtin_amdgcn_mfma_f32_32x32x16_f16(af, ldfrag4(wt, bRow2 + o), A2, 0, 0, 0);
            A3 = __builtin_amdgcn_mfma_f32_32x32x16_f16(af, ldfrag4(wt, bRow3 + o), A3, 0, 0, 0);
        }
    };
    #define ROW_OF(reg) (rt*32 + ((reg)&3) + 8*((reg)>>2) + 4*grp)

    auto act_st = [&](int row, int col, float v){
        unsigned int d = SWZ(row, col >> 1);
        Act[row*128 + (d << 1) + (col & 1)] = (_Float16)v;
    };

    // ================= layer e1 (129 -> 128) =================
    {
        float w00 = W_e1[ln31],      w01 = W_e1[32+ln31];
        float w02 = W_e1[64+ln31],   w03 = W_e1[96+ln31];
        float bz0 = b_e1[ln31],      bz1 = b_e1[32+ln31];
        float bz2 = b_e1[64+ln31],   bz3 = b_e1[96+ln31];
        f32x16 a0, a1, a2, a3;
        #pragma unroll
        for (int reg = 0; reg < 16; ++reg){
            float dv = dls[ROW_OF(reg)];
            a0[reg] = fmaf(dv, w00, bz0);
            a1[reg] = fmaf(dv, w01, bz1);
            a2[reg] = fmaf(dv, w02, bz2);
            a3[reg] = fmaf(dv, w03, bz3);
        }
        gemm4(a0, a1, a2, a3);
        __syncthreads();
        #pragma unroll
        for (int reg = 0; reg < 16; ++reg){
            int row = ROW_OF(reg);
            act_st(row, ln31,      selu_f(a0[reg]));
            act_st(row, 32 + ln31, selu_f(a1[reg]));
            act_st(row, 64 + ln31, selu_f(a2[reg]));
            act_st(row, 96 + ln31, selu_f(a3[reg]));
        }
        stage_wt(WTg + 16384);
        __syncthreads();
    }

    // ================= layer e2 (128 -> 128), e_sum fused =================
    {
        float bz0 = b_e2[ln31],    bz1 = b_e2[32+ln31];
        float bz2 = b_e2[64+ln31], bz3 = b_e2[96+ln31];
        f32x16 a0, a1, a2, a3;
        #pragma unroll
        for (int reg = 0; reg < 16; ++reg){ a0[reg]=bz0; a1[reg]=bz1; a2[reg]=bz2; a3[reg]=bz3; }
        gemm4(a0, a1, a2, a3);
        __syncthreads();
        float e0[16], e1v[16], e2v[16], e3[16];
        float sl0=0.f, sh0=0.f, sl1=0.f, sh1=0.f, sl2=0.f, sh2=0.f, sl3=0.f, sh3=0.f;
        #pragma unroll
        for (int reg = 0; reg < 16; ++reg){
            e0[reg]=selu_f(a0[reg]); e1v[reg]=selu_f(a1[reg]);
            e2v[reg]=selu_f(a2[reg]); e3[reg]=selu_f(a3[reg]);
            if (reg < 8){ sl0+=e0[reg]; sl1+=e1v[reg]; sl2+=e2v[reg]; sl3+=e3[reg]; }
            else        { sh0+=e0[reg]; sh1+=e1v[reg]; sh2+=e2v[reg]; sh3+=e3[reg]; }
        }
        sl0 += __shfl_xor(sl0, 32, 64);  sh0 += __shfl_xor(sh0, 32, 64);
        sl1 += __shfl_xor(sl1, 32, 64);  sh1 += __shfl_xor(sh1, 32, 64);
        sl2 += __shfl_xor(sl2, 32, 64);  sh2 += __shfl_xor(sh2, 32, 64);
        sl3 += __shfl_xor(sl3, 32, 64);  sh3 += __shfl_xor(sh3, 32, 64);
        if (grp == 0){
            agg[rt*2+0][ln31]      = sl0;  agg[rt*2+1][ln31]      = sh0;
            agg[rt*2+0][32 + ln31] = sl1;  agg[rt*2+1][32 + ln31] = sh1;
            agg[rt*2+0][64 + ln31] = sl2;  agg[rt*2+1][64 + ln31] = sh2;
            agg[rt*2+0][96 + ln31] = sl3;  agg[rt*2+1][96 + ln31] = sh3;
        }
        #pragma unroll
        for (int reg = 0; reg < 16; ++reg){
            int row = ROW_OF(reg);
            act_st(row, ln31,      e0[reg]);
            act_st(row, 32 + ln31, e1v[reg]);
            act_st(row, 64 + ln31, e2v[reg]);
            act_st(row, 96 + ln31, e3[reg]);
        }
        stage_wt(WTg + 2*16384);
        __syncthreads();
    }

    // ================= layer c1 (128 -> 128) + c2 fused =================
    {
        float bz0 = b_c1[ln31],    bz1 = b_c1[32+ln31];
        float bz2 = b_c1[64+ln31], bz3 = b_c1[96+ln31];
        f32x16 a0, a1, a2, a3;
        #pragma unroll
        for (int reg = 0; reg < 16; ++reg){ a0[reg]=bz0; a1[reg]=bz1; a2[reg]=bz2; a3[reg]=bz3; }
        gemm4(a0, a1, a2, a3);
        __syncthreads();
        float wc0 = W_c2[ln31],    wc1 = W_c2[32+ln31];
        float wc2 = W_c2[64+ln31], wc3 = W_c2[96+ln31];
        float bc2 = b_c2[0];
        float p[16];
        #pragma unroll
        for (int reg = 0; reg < 16; ++reg)
            p[reg] = selu_f(a0[reg])*wc0 + selu_f(a1[reg])*wc1
                   + selu_f(a2[reg])*wc2 + selu_f(a3[reg])*wc3;
        #pragma unroll
        for (int msk = 16; msk > 0; msk >>= 1){
            #pragma unroll
            for (int reg = 0; reg < 16; ++reg)
                p[reg] += __shfl_xor(p[reg], msk, 64);
        }
        if (ln31 == 0){
            #pragma unroll
            for (int reg = 0; reg < 16; ++reg)
                wedge[ROW_OF(reg)] = bc2 + p[reg];
        }
        __syncthreads();
    }

    // ================= epilogue: coords, fp16 agg writeback =================
    if (tid < 3*NPB){
        int nd = tid / 3, c = tid - nd*3;
        int gi = min(g0 + nd, n - 1);
        float ci = coords[3*gi + c];
        float s = 0.f;
        #pragma unroll
        for (int k = 0; k < KNB; ++k){
            int e = nd*KNB + k;
            s += (ci - coords[3*nb[e] + c]) * wedge[e];
        }
        if (g0 + nd < n) out_coords[3*gi + c] = ci + s * (1.0f/KNB);
    }

    for (int s = tid; s < NPB*96; s += 256){
        int nd = s / 96, c2 = s - nd*96;
        if (g0 + nd < n){
            int c = c2 * 2;
            float v0 = (c   < HDIM) ? agg[nd][c]
                                    : h[(size_t)j0s[nd]*FDIM + (c - HDIM)];
            float v1 = (c+1 < HDIM) ? agg[nd][c+1]
                                    : h[(size_t)j0s[nd]*FDIM + (c+1 - HDIM)];
            aggout[(size_t)(g0 + nd)*96 + c2] = pack2(v0, v1);
        }
    }
}

// ---------------------------------------------------------------------------
// Kernel 3: node MLP as MFMA. 128 nodes/block (79 blocks).
// ---------------------------------------------------------------------------
__global__ __launch_bounds__(256, 2) void node_mlp_kernel(
    const unsigned int* __restrict__ aggin,   // n rows x 96 dwords (192 f16)
    const _Float16* __restrict__ WN1T, const float* __restrict__ b_n1,
    const _Float16* __restrict__ WN2T, const float* __restrict__ b_n2,
    float* __restrict__ out, int n)
{
    __shared__ __attribute__((aligned(16))) unsigned int Act[128 * 96]; // 49152 B
    _Float16* acth = (_Float16*)Act;

    const int g0  = blockIdx.x * 128;
    const int tid = threadIdx.x;
    const int lane = tid & 63, wid = tid >> 6;
    const int ln31 = lane & 31, grp = lane >> 5;
    const int rt  = wid;

    // ---- stage 128 rows x 96 dwords, swizzled ----
    const int maxch = n * 24 - 1;
    #pragma unroll
    for (int q = 0; q < 12; ++q){
        int ch = q * 256 + tid;               // 0..3071
        int r  = ch / 24, c = ch - r * 24;
        int gch = min(g0 * 24 + ch, maxch);
        uint4 v = *(const uint4*)(aggin + (size_t)gch * 4);
        *(uint4*)(Act + r * 96 + SWZ(r, 4 * c)) = v;
    }
    __syncthreads();

    const unsigned int sA   = ((unsigned int)ln31 & 7u) << 2;
    const unsigned int aRow = (unsigned int)(rt*32 + ln31) * 96;
    #define ROW_OF(reg) (rt*32 + ((reg)&3) + 8*((reg)>>2) + 4*grp)

    // ---- layer n1: K=192 ----
    f32x16 a0, a1, a2, a3;
    {
        float bz0 = b_n1[ln31],    bz1 = b_n1[32+ln31];
        float bz2 = b_n1[64+ln31], bz3 = b_n1[96+ln31];
        #pragma unroll
        for (int reg = 0; reg < 16; ++reg){ a0[reg]=bz0; a1[reg]=bz1; a2[reg]=bz2; a3[reg]=bz3; }
        const _Float16* w0 = WN1T + (size_t)(ln31      ) * 192 + grp*8;
        const _Float16* w1 = WN1T + (size_t)(32 + ln31 ) * 192 + grp*8;
        const _Float16* w2 = WN1T + (size_t)(64 + ln31 ) * 192 + grp*8;
        const _Float16* w3 = WN1T + (size_t)(96 + ln31 ) * 192 + grp*8;
        #pragma unroll
        for (int ks = 0; ks < 12; ++ks){
            const unsigned int o = ((unsigned int)(ks*8 + grp*4)) ^ sA;
            f16x8 af = ldfrag4(Act, aRow + o);
            a0 = __builtin_amdgcn_mfma_f32_32x32x16_f16(af, ldg8h(w0 + ks*16), a0, 0, 0, 0);
            a1 = __builtin_amdgcn_mfma_f32_32x32x16_f16(af, ldg8h(w1 + ks*16), a1, 0, 0, 0);
            a2 = __builtin_amdgcn_mfma_f32_32x32x16_f16(af, ldg8h(w2 + ks*16), a2, 0, 0, 0);
            a3 = __builtin_amdgcn_mfma_f32_32x32x16_f16(af, ldg8h(w3 + ks*16), a3, 0, 0, 0);
        }
    }
    __syncthreads();
    // selu + writeback into own rows
    #pragma unroll
    for (int reg = 0; reg < 16; ++reg){
        int row = ROW_OF(reg);
        #pragma unroll
        for (int t = 0; t < 4; ++t){
            int col = t*32 + ln31;
            float v = (t==0) ? a0[reg] : (t==1) ? a1[reg] : (t==2) ? a2[reg] : a3[reg];
            unsigned int d = SWZ(row, col >> 1);
            acth[row*192 + (d << 1) + (col & 1)] = (_Float16)selu_f(v);
        }
    }
    __syncthreads();

    // ---- layer n2: K=128 ----
    {
        float bz0 = b_n2[ln31],    bz1 = b_n2[32+ln31];
        float bz2 = b_n2[64+ln31], bz3 = b_n2[96+ln31];
        #pragma unroll
        for (int reg = 0; reg < 16; ++reg){ a0[reg]=bz0; a1[reg]=bz1; a2[reg]=bz2; a3[reg]=bz3; }
        const _Float16* w0 = WN2T + (size_t)(ln31      ) * 128 + grp*8;
        const _Float16* w1 = WN2T + (size_t)(32 + ln31 ) * 128 + grp*8;
        const _Float16* w2 = WN2T + (size_t)(64 + ln31 ) * 128 + grp*8;
        const _Float16* w3 = WN2T + (size_t)(96 + ln31 ) * 128 + grp*8;
        #pragma unroll
        for (int ks = 0; ks < 8; ++ks){
            const unsigned int o = ((unsigned int)(ks*8 + grp*4)) ^ sA;
            f16x8 af = ldfrag4(Act, aRow + o);
            a0 = __builtin_amdgcn_mfma_f32_32x32x16_f16(af, ldg8h(w0 + ks*16), a0, 0, 0, 0);
            a1 = __builtin_amdgcn_mfma_f32_32x32x16_f16(af, ldg8h(w1 + ks*16), a1, 0, 0, 0);
            a2 = __builtin_amdgcn_mfma_f32_32x32x16_f16(af, ldg8h(w2 + ks*16), a2, 0, 0, 0);
            a3 = __builtin_amdgcn_mfma_f32_32x32x16_f16(af, ldg8h(w3 + ks*16), a3, 0, 0, 0);
        }
    }
    // ---- write out ----
    #pragma unroll
    for (int reg = 0; reg < 16; ++reg){
        int row = ROW_OF(reg);
        int node = g0 + row;
        if (node < n){
            float* op = out + (size_t)node * HDIM;
            op[ln31]      = a0[reg];
            op[32 + ln31] = a1[reg];
            op[64 + ln31] = a2[reg];
            op[96 + ln31] = a3[reg];
        }
    }
    #undef ROW_OF
}

extern "C" void kernel_launch(void* const* d_in, const int* in_sizes, int n_in,
                              void* d_out, int out_size, void* d_ws, size_t ws_size,
                              hipStream_t stream)
{
    const float* h          = (const float*)d_in[0];
    const float* coords     = (const float*)d_in[1];
    const int*   row_splits = (const int*)  d_in[2];
    const float* W_e1 = (const float*)d_in[3];
    const float* b_e1 = (const float*)d_in[4];
    const float* W_e2 = (const float*)d_in[5];
    const float* b_e2 = (const float*)d_in[6];
    const float* W_c1 = (const float*)d_in[7];
    const float* b_c1 = (const float*)d_in[8];
    const float* W_c2 = (const float*)d_in[9];
    const float* b_c2 = (const float*)d_in[10];
    const float* W_n1 = (const float*)d_in[11];
    const float* b_n1 = (const float*)d_in[12];
    const float* W_n2 = (const float*)d_in[13];
    const float* b_n2 = (const float*)d_in[14];

    const int n    = in_sizes[0] / FDIM;
    const int nseg = in_sizes[2] - 1;
    const int npad = n + PADN;

    float* out        = (float*)d_out;
    float* out_coords = out + (size_t)n * HDIM;
    float* out_nidx   = out_coords + (size_t)n * 3;
    float* out_d      = out_nidx + (size_t)n * KNB;

    int*          nidx_i = (int*)d_ws;
    float*        ndist  = (float*)(nidx_i + (size_t)n * KNB);
    int*          idx0   = (int*)(ndist + (size_t)n * KNB);
    _Float16*     WT     = (_Float16*)(idx0 + (size_t)n);     // 3 x 128x128 f16
    _Float16*     WN1T   = WT + 3 * 16384;                    // 128x192 f16
    _Float16*     WN2T   = WN1T + 128 * 192;                  // 128x128 f16
    unsigned int* aggbuf = (unsigned int*)(WN2T + 128 * 128); // n x 96 dwords
    float4*       c4     = (float4*)(aggbuf + (size_t)n * 96);// npad x float4

    const int prep_blocks = 352 + (npad + 255) / 256;
    prep_kernel<<<prep_blocks, 256, 0, stream>>>(W_e1, W_e2, W_c1, WT,
                                                 W_n1, WN1T, W_n2, WN2T,
                                                 coords, c4, n, npad);

    knn_kernel<<<n, 64, 0, stream>>>(c4, row_splits, nseg, n,
                                     nidx_i, ndist, idx0, out_nidx, out_d);

    egcn_node_kernel<<<(n + NPB - 1) / NPB, 256, 0, stream>>>(
        h, coords, nidx_i, ndist, idx0, WT,
        W_e1, b_e1, b_e2, b_c1, W_c2, b_c2,
        aggbuf, out_coords, n);

    node_mlp_kernel<<<(n + 127) / 128, 256, 0, stream>>>(
        aggbuf, WN1T, b_n1, WN2T, b_n2, out, n);
}

// Round 16
// 245.757 us; speedup vs baseline: 1.0053x; 1.0053x over previous
//
#include <hip/hip_runtime.h>
#include <cstdint>

#define KNB 16
#define FDIM 64
#define HDIM 128
#define NPB 8           // nodes per egcn block
#define ROWS 128        // edge rows per egcn block
#define CMAXW 80        // candidates per lane (segments up to 5120)
#define PADN 5120       // c4 padding entries

typedef unsigned long long ull;
typedef _Float16 f16x8 __attribute__((ext_vector_type(8)));
typedef float    f32x16 __attribute__((ext_vector_type(16)));

__device__ __forceinline__ float selu_f(float x){
    const float a = 1.6732632423543772f, s = 1.0507009873554805f;
    return x > 0.f ? s * x : s * a * (__expf(x) - 1.0f);
}

__device__ __forceinline__ unsigned int pack2(float a, float b){
    union { _Float16 h[2]; unsigned int u; } t;
    t.h[0] = (_Float16)a; t.h[1] = (_Float16)b;
    return t.u;
}

__device__ __forceinline__ f16x8 ldfrag4(const unsigned int* p, unsigned int di){
    union { uint4 q; f16x8 v; } t;
    t.q = *(const uint4*)(p + di);
    return t.v;
}

__device__ __forceinline__ f16x8 ldg8h(const _Float16* p){
    union { uint4 q; f16x8 v; } t;
    t.q = *(const uint4*)p;
    return t.v;
}

// ---- u32 min-reduce across a wave64 in pure-VALU DPP ----
template<int CTRL>
__device__ __forceinline__ unsigned int dppmin_u32(unsigned int v){
    unsigned int t = (unsigned int)__builtin_amdgcn_update_dpp(
        -1, (int)v, CTRL, 0xF, 0xF, false);
    return t < v ? t : v;
}
__device__ __forceinline__ unsigned int wave_min_u32(unsigned int v){
    v = dppmin_u32<0x111>(v);
    v = dppmin_u32<0x112>(v);
    v = dppmin_u32<0x114>(v);
    v = dppmin_u32<0x118>(v);
    v = dppmin_u32<0x142>(v);
    v = dppmin_u32<0x143>(v);
    return (unsigned int)__builtin_amdgcn_readlane((int)v, 63);
}

#define SWZ(row, d) ((unsigned int)(d) ^ ((((unsigned int)(row)) & 7u) << 2))

// ---------------------------------------------------------------------------
// Kernel 0: fused prep.
//  b in [0,192):   WT[n][k]   = W_e*[k][n] fp16 (3 x 128x128)
//  b in [192,288): WN1T[n][k] = W_n1[k][n] fp16 (128x192)
//  b in [288,352): WN2T[n][k] = W_n2[k][n] fp16 (128x128)
//  b >= 352:       c4[j] = {x,y,z,nrm}; pad = {0,0,0,+inf}
// ---------------------------------------------------------------------------
__global__ __launch_bounds__(256) void prep_kernel(
    const float* __restrict__ We1, const float* __restrict__ We2,
    const float* __restrict__ Wc1, _Float16* __restrict__ WT,
    const float* __restrict__ Wn1, _Float16* __restrict__ WN1T,
    const float* __restrict__ Wn2, _Float16* __restrict__ WN2T,
    const float* __restrict__ coords, float4* __restrict__ c4, int n, int npad)
{
    int b = blockIdx.x;
    if (b < 192){
        int id = b * 256 + threadIdx.x;
        int m  = id >> 14;
        int r  = id & 16383;
        int nn = (r >> 7) & 127;
        int k  = r & 127;
        float v;
        if (m == 0)      v = We1[(k + 1) * 128 + nn];
        else if (m == 1) v = We2[k * 128 + nn];
        else             v = Wc1[k * 128 + nn];
        WT[m * 16384 + nn * 128 + k] = (_Float16)v;
    } else if (b < 288){
        int id = (b - 192) * 256 + threadIdx.x;   // 0..24575
        int nn = id / 192, k = id - nn * 192;
        WN1T[nn * 192 + k] = (_Float16)Wn1[k * 128 + nn];
    } else if (b < 352){
        int id = (b - 288) * 256 + threadIdx.x;   // 0..16383
        int nn = id >> 7, k = id & 127;
        WN2T[nn * 128 + k] = (_Float16)Wn2[k * 128 + nn];
    } else {
        int i = (b - 352) * 256 + threadIdx.x;
        if (i < n){
            float x = coords[3*i], y = coords[3*i+1], z = coords[3*i+2];
            float nrm = __fadd_rn(__fadd_rn(__fmul_rn(x,x), __fmul_rn(y,y)), __fmul_rn(z,z));
            c4[i] = make_float4(x, y, z, nrm);
        } else if (i < npad){
            c4[i] = make_float4(0.f, 0.f, 0.f, __uint_as_float(0x7f800000u));
        }
    }
}

// ---------------------------------------------------------------------------
// Kernel 1: exact KNN, one wave per block (grid = n). R14 config — the
// empirical best (95.5us). R15 post-mortem: manual double-buffered loads
// collapsed to VGPR 40 and regressed to 105us; R13 dual chains blew VGPR to
// 132 (257us). The serial u64 top-3 insert chain at ~6000 inst/wave, 52%
// VALUBusy is this algorithm's practical floor.
// ---------------------------------------------------------------------------
__global__ __launch_bounds__(64) void knn_kernel(
    const float4* __restrict__ c4,
    const int* __restrict__ row_splits, int nseg, int n,
    int* __restrict__ nidx, float* __restrict__ ndist, int* __restrict__ idx0,
    float* __restrict__ out_nidx, float* __restrict__ out_d)
{
    const int lane = threadIdx.x;
    const int i    = blockIdx.x;
    if (i >= n) return;

    int lo = 0, hi = n;
    for (int s = 0; s < nseg; ++s){
        int a = row_splits[s], b = row_splits[s+1];
        if (i >= a && i < b){ lo = a; hi = b; }
    }

    const float4 ci = c4[i];
    const float cx = ci.x, cy = ci.y, cz = ci.z, nrmi = ci.w;

    const int jbase = lo + lane;
    const float FINF = __uint_as_float(0x7f800000u);

    ull m1 = ~0ull, m2 = ~0ull, m3 = ~0ull;

    #define D2_OF(v) __fsub_rn(__fadd_rn(nrmi, (v).w), __fmul_rn(2.0f, \
        __fadd_rn(__fadd_rn(__fmul_rn(cx,(v).x), __fmul_rn(cy,(v).y)), __fmul_rn(cz,(v).z))))
    #define INS(kk) { \
        ull n1 = (kk) < m1 ? (kk) : m1; \
        ull t1 = (kk) < m1 ? m1 : (kk); \
        ull n2 = t1 < m2 ? t1 : m2; \
        ull t2 = t1 < m2 ? m2 : t1; \
        ull n3 = t2 < m3 ? t2 : m3; \
        m1 = n1; m2 = n2; m3 = n3; }

    for (int c0 = 0; c0 < CMAXW; c0 += 8){
        float4 v[8]; int jj[8];
        #pragma unroll
        for (int q = 0; q < 8; ++q){
            jj[q] = jbase + (c0 + q)*64;
            v[q]  = c4[jj[q]];            // pad region returns {0,0,0,inf}
        }
        #pragma unroll
        for (int q = 0; q < 8; ++q){
            float dv = (jj[q] < hi) ? fmaxf(D2_OF(v[q]), 0.0f) : FINF;
            ull kk = (((ull)__float_as_uint(dv)) << 32) | (unsigned int)jj[q];
            INS(kk)
        }
    }
    int vcnt = 3;

    for (int r = 0; r < KNB + 1; ++r){
        unsigned int h32 = (unsigned int)(m1 >> 32);
        unsigned int l32 = (unsigned int)m1;
        unsigned int wmd = wave_min_u32(h32);
        unsigned int jm  = (h32 == wmd) ? l32 : 0xFFFFFFFFu;
        unsigned int wmj = wave_min_u32(jm);

        bool own = (h32 == wmd) && (l32 == wmj);
        bool need = false;
        if (own){
            int   j  = (int)wmj;
            float dv = __uint_as_float(wmd);
            if (r == 0){
                idx0[i] = j;
            } else {
                int rr = r - 1;
                nidx[i*KNB + rr]     = j;
                ndist[i*KNB + rr]    = dv;
                out_nidx[i*KNB + rr] = (float)j;
                out_d[i*KNB + rr]    = dv;
            }
            m1 = m2; m2 = m3; m3 = ~0ull;
            need = (--vcnt == 0);
        }

        if (__ballot((int)need)){   // wave-uniform: body never issues if untaken
            if (need){
                ull b = (((ull)wmd) << 32) | wmj;
                m1 = m2 = m3 = ~0ull;
                for (int c = 0; c < CMAXW; ++c){
                    int j = jbase + c*64;
                    float4 v = c4[j];
                    float dv = (j < hi) ? fmaxf(D2_OF(v), 0.0f) : FINF;
                    ull kk = (((ull)__float_as_uint(dv)) << 32) | (unsigned int)j;
                    kk = kk > b ? kk : ~0ull;
                    INS(kk)
                }
                vcnt = 3;
            }
        }
    }
    #undef INS
    #undef D2_OF
}

// ---------------------------------------------------------------------------
// Kernel 2: egcn, R10 structure (LDS wt staging, XOR swizzle, (256,2) — the
// no-spill config). aggbuf written as fp16 for the MFMA node MLP.
// ---------------------------------------------------------------------------
__global__ __launch_bounds__(256, 2) void egcn_node_kernel(
    const float* __restrict__ h, const float* __restrict__ coords,
    const int* __restrict__ nidx, const float* __restrict__ ndist,
    const int* __restrict__ idx0, const _Float16* __restrict__ WTg,
    const float* __restrict__ W_e1, const float* __restrict__ b_e1,
    const float* __restrict__ b_e2, const float* __restrict__ b_c1,
    const float* __restrict__ W_c2, const float* __restrict__ b_c2,
    unsigned int* __restrict__ aggout, float* __restrict__ out_coords, int n)
{
    __shared__ __attribute__((aligned(16))) _Float16 Act[ROWS * 128];   // 32768 B
    __shared__ __attribute__((aligned(16))) unsigned int wt[ROWS * 64]; // 32768 B
    __shared__ float agg[NPB][HDIM];                                    // 4096 B
    __shared__ float dls[ROWS];
    __shared__ int   nb[ROWS];
    __shared__ int   j0s[NPB];
    __shared__ float wedge[ROWS];

    const int g0  = blockIdx.x * NPB;
    const int tid = threadIdx.x;
    const int lane = tid & 63, wid = tid >> 6;
    const int ln31 = lane & 31, grp = lane >> 5;
    const int rt  = wid;                 // row tile 0..3 (32 edge rows each)

    if (tid < ROWS){
        int e = min(g0*KNB + tid, n*KNB - 1);
        nb[tid]  = nidx[e];
        dls[tid] = ndist[e];
    }
    if (tid < NPB) j0s[tid] = idx0[min(g0 + tid, n - 1)];
    __syncthreads();

    unsigned int* actd = (unsigned int*)Act;

    // ---- stage Act = [h_self | h_neig] fp16, float4 loads + swizzled b128 ----
    {
        int r = tid >> 1, half = tid & 1;
        const float4* hs = (const float4*)(h + (size_t)j0s[r >> 4] * FDIM + half*32);
        const float4* hn = (const float4*)(h + (size_t)nb[r] * FDIM + half*32);
        unsigned int rb = (unsigned int)r * 64;
        uint4 buf[4];
        #pragma unroll
        for (int q = 0; q < 4; ++q){
            float4 a = hs[2*q], b = hs[2*q+1];
            buf[q].x = pack2(a.x,a.y); buf[q].y = pack2(a.z,a.w);
            buf[q].z = pack2(b.x,b.y); buf[q].w = pack2(b.z,b.w);
        }
        #pragma unroll
        for (int q = 0; q < 4; ++q)
            *(uint4*)(actd + rb + SWZ(r, half*16 + 4*q)) = buf[q];
        #pragma unroll
        for (int q = 0; q < 4; ++q){
            float4 a = hn[2*q], b = hn[2*q+1];
            buf[q].x = pack2(a.x,a.y); buf[q].y = pack2(a.z,a.w);
            buf[q].z = pack2(b.x,b.y); buf[q].w = pack2(b.z,b.w);
        }
        #pragma unroll
        for (int q = 0; q < 4; ++q)
            *(uint4*)(actd + rb + SWZ(r, 32 + half*16 + 4*q)) = buf[q];
    }
    auto stage_wt = [&](const _Float16* Wg){
        int nr = tid >> 1, half = tid & 1;
        const uint4* src = (const uint4*)(Wg + nr * 128 + half*64);
        unsigned int rb = (unsigned int)nr * 64;
        #pragma unroll
        for (int q = 0; q < 8; ++q)
            *(uint4*)(wt + rb + SWZ(nr, half*32 + q*4)) = src[q];
    };
    stage_wt(WTg);
    __syncthreads();

    const unsigned int sA    = ((unsigned int)ln31 & 7u) << 2;
    const unsigned int aRow  = (unsigned int)(rt*32 + ln31) * 64;
    const unsigned int bRow0 = (unsigned int)(ln31      ) * 64;
    const unsigned int bRow1 = (unsigned int)(32  + ln31) * 64;
    const unsigned int bRow2 = (unsigned int)(64  + ln31) * 64;
    const unsigned int bRow3 = (unsigned int)(96  + ln31) * 64;

    auto gemm4 = [&](f32x16& A0, f32x16& A1, f32x16& A2, f32x16& A3){
        #pragma unroll
        for (int ks = 0; ks < 8; ++ks){
            const unsigned int o = ((unsigned int)(ks*8 + grp*4)) ^ sA;
            f16x8 af = ldfrag4(actd, aRow + o);
            A0 = __builtin_amdgcn_mfma_f32_32x32x16_f16(af, ldfrag4(wt, bRow0 + o), A0, 0, 0, 0);
            A1 = __builtin_amdgcn_mfma_f32_32x32x16_f16(af, ldfrag4(wt, bRow1 + o), A1, 0, 0, 0);
            A2 = __builtin_amdgcn_mfma_f32_32x32x16_f16(af, ldfrag4(wt, bRow2 + o), A2, 0, 0, 0);
            A3 = __builtin_amdgcn_mfma_f32_32x32x16_f16(af, ldfrag4(wt, bRow3 + o), A3, 0, 0, 0);
        }
    };
    #define ROW_OF(reg) (rt*32 + ((reg)&3) + 8*((reg)>>2) + 4*grp)

    auto act_st = [&](int row, int col, float v){
        unsigned int d = SWZ(row, col >> 1);
        Act[row*128 + (d << 1) + (col & 1)] = (_Float16)v;
    };

    // ================= layer e1 (129 -> 128) =================
    {
        float w00 = W_e1[ln31],      w01 = W_e1[32+ln31];
        float w02 = W_e1[64+ln31],   w03 = W_e1[96+ln31];
        float bz0 = b_e1[ln31],      bz1 = b_e1[32+ln31];
        float bz2 = b_e1[64+ln31],   bz3 = b_e1[96+ln31];
        f32x16 a0, a1, a2, a3;
        #pragma unroll
        for (int reg = 0; reg < 16; ++reg){
            float dv = dls[ROW_OF(reg)];
            a0[reg] = fmaf(dv, w00, bz0);
            a1[reg] = fmaf(dv, w01, bz1);
            a2[reg] = fmaf(dv, w02, bz2);
            a3[reg] = fmaf(dv, w03, bz3);
        }
        gemm4(a0, a1, a2, a3);
        __syncthreads();
        #pragma unroll
        for (int reg = 0; reg < 16; ++reg){
            int row = ROW_OF(reg);
            act_st(row, ln31,      selu_f(a0[reg]));
            act_st(row, 32 + ln31, selu_f(a1[reg]));
            act_st(row, 64 + ln31, selu_f(a2[reg]));
            act_st(row, 96 + ln31, selu_f(a3[reg]));
        }
        stage_wt(WTg + 16384);
        __syncthreads();
    }

    // ================= layer e2 (128 -> 128), e_sum fused =================
    {
        float bz0 = b_e2[ln31],    bz1 = b_e2[32+ln31];
        float bz2 = b_e2[64+ln31], bz3 = b_e2[96+ln31];
        f32x16 a0, a1, a2, a3;
        #pragma unroll
        for (int reg = 0; reg < 16; ++reg){ a0[reg]=bz0; a1[reg]=bz1; a2[reg]=bz2; a3[reg]=bz3; }
        gemm4(a0, a1, a2, a3);
        __syncthreads();
        float e0[16], e1v[16], e2v[16], e3[16];
        float sl0=0.f, sh0=0.f, sl1=0.f, sh1=0.f, sl2=0.f, sh2=0.f, sl3=0.f, sh3=0.f;
        #pragma unroll
        for (int reg = 0; reg < 16; ++reg){
            e0[reg]=selu_f(a0[reg]); e1v[reg]=selu_f(a1[reg]);
            e2v[reg]=selu_f(a2[reg]); e3[reg]=selu_f(a3[reg]);
            if (reg < 8){ sl0+=e0[reg]; sl1+=e1v[reg]; sl2+=e2v[reg]; sl3+=e3[reg]; }
            else        { sh0+=e0[reg]; sh1+=e1v[reg]; sh2+=e2v[reg]; sh3+=e3[reg]; }
        }
        sl0 += __shfl_xor(sl0, 32, 64);  sh0 += __shfl_xor(sh0, 32, 64);
        sl1 += __shfl_xor(sl1, 32, 64);  sh1 += __shfl_xor(sh1, 32, 64);
        sl2 += __shfl_xor(sl2, 32, 64);  sh2 += __shfl_xor(sh2, 32, 64);
        sl3 += __shfl_xor(sl3, 32, 64);  sh3 += __shfl_xor(sh3, 32, 64);
        if (grp == 0){
            agg[rt*2+0][ln31]      = sl0;  agg[rt*2+1][ln31]      = sh0;
            agg[rt*2+0][32 + ln31] = sl1;  agg[rt*2+1][32 + ln31] = sh1;
            agg[rt*2+0][64 + ln31] = sl2;  agg[rt*2+1][64 + ln31] = sh2;
            agg[rt*2+0][96 + ln31] = sl3;  agg[rt*2+1][96 + ln31] = sh3;
        }
        #pragma unroll
        for (int reg = 0; reg < 16; ++reg){
            int row = ROW_OF(reg);
            act_st(row, ln31,      e0[reg]);
            act_st(row, 32 + ln31, e1v[reg]);
            act_st(row, 64 + ln31, e2v[reg]);
            act_st(row, 96 + ln31, e3[reg]);
        }
        stage_wt(WTg + 2*16384);
        __syncthreads();
    }

    // ================= layer c1 (128 -> 128) + c2 fused =================
    {
        float bz0 = b_c1[ln31],    bz1 = b_c1[32+ln31];
        float bz2 = b_c1[64+ln31], bz3 = b_c1[96+ln31];
        f32x16 a0, a1, a2, a3;
        #pragma unroll
        for (int reg = 0; reg < 16; ++reg){ a0[reg]=bz0; a1[reg]=bz1; a2[reg]=bz2; a3[reg]=bz3; }
        gemm4(a0, a1, a2, a3);
        __syncthreads();
        float wc0 = W_c2[ln31],    wc1 = W_c2[32+ln31];
        float wc2 = W_c2[64+ln31], wc3 = W_c2[96+ln31];
        float bc2 = b_c2[0];
        float p[16];
        #pragma unroll
        for (int reg = 0; reg < 16; ++reg)
            p[reg] = selu_f(a0[reg])*wc0 + selu_f(a1[reg])*wc1
                   + selu_f(a2[reg])*wc2 + selu_f(a3[reg])*wc3;
        #pragma unroll
        for (int msk = 16; msk > 0; msk >>= 1){
            #pragma unroll
            for (int reg = 0; reg < 16; ++reg)
                p[reg] += __shfl_xor(p[reg], msk, 64);
        }
        if (ln31 == 0){
            #pragma unroll
            for (int reg = 0; reg < 16; ++reg)
                wedge[ROW_OF(reg)] = bc2 + p[reg];
        }
        __syncthreads();
    }

    // ================= epilogue: coords, fp16 agg writeback =================
    if (tid < 3*NPB){
        int nd = tid / 3, c = tid - nd*3;
        int gi = min(g0 + nd, n - 1);
        float ci = coords[3*gi + c];
        float s = 0.f;
        #pragma unroll
        for (int k = 0; k < KNB; ++k){
            int e = nd*KNB + k;
            s += (ci - coords[3*nb[e] + c]) * wedge[e];
        }
        if (g0 + nd < n) out_coords[3*gi + c] = ci + s * (1.0f/KNB);
    }

    for (int s = tid; s < NPB*96; s += 256){
        int nd = s / 96, c2 = s - nd*96;
        if (g0 + nd < n){
            int c = c2 * 2;
            float v0 = (c   < HDIM) ? agg[nd][c]
                                    : h[(size_t)j0s[nd]*FDIM + (c - HDIM)];
            float v1 = (c+1 < HDIM) ? agg[nd][c+1]
                                    : h[(size_t)j0s[nd]*FDIM + (c+1 - HDIM)];
            aggout[(size_t)(g0 + nd)*96 + c2] = pack2(v0, v1);
        }
    }
}

// ---------------------------------------------------------------------------
// Kernel 3: node MLP as MFMA. 128 nodes/block (79 blocks).
// ---------------------------------------------------------------------------
__global__ __launch_bounds__(256, 2) void node_mlp_kernel(
    const unsigned int* __restrict__ aggin,   // n rows x 96 dwords (192 f16)
    const _Float16* __restrict__ WN1T, const float* __restrict__ b_n1,
    const _Float16* __restrict__ WN2T, const float* __restrict__ b_n2,
    float* __restrict__ out, int n)
{
    __shared__ __attribute__((aligned(16))) unsigned int Act[128 * 96]; // 49152 B
    _Float16* acth = (_Float16*)Act;

    const int g0  = blockIdx.x * 128;
    const int tid = threadIdx.x;
    const int lane = tid & 63, wid = tid >> 6;
    const int ln31 = lane & 31, grp = lane >> 5;
    const int rt  = wid;

    // ---- stage 128 rows x 96 dwords, swizzled ----
    const int maxch = n * 24 - 1;
    #pragma unroll
    for (int q = 0; q < 12; ++q){
        int ch = q * 256 + tid;               // 0..3071
        int r  = ch / 24, c = ch - r * 24;
        int gch = min(g0 * 24 + ch, maxch);
        uint4 v = *(const uint4*)(aggin + (size_t)gch * 4);
        *(uint4*)(Act + r * 96 + SWZ(r, 4 * c)) = v;
    }
    __syncthreads();

    const unsigned int sA   = ((unsigned int)ln31 & 7u) << 2;
    const unsigned int aRow = (unsigned int)(rt*32 + ln31) * 96;
    #define ROW_OF(reg) (rt*32 + ((reg)&3) + 8*((reg)>>2) + 4*grp)

    // ---- layer n1: K=192 ----
    f32x16 a0, a1, a2, a3;
    {
        float bz0 = b_n1[ln31],    bz1 = b_n1[32+ln31];
        float bz2 = b_n1[64+ln31], bz3 = b_n1[96+ln31];
        #pragma unroll
        for (int reg = 0; reg < 16; ++reg){ a0[reg]=bz0; a1[reg]=bz1; a2[reg]=bz2; a3[reg]=bz3; }
        const _Float16* w0 = WN1T + (size_t)(ln31      ) * 192 + grp*8;
        const _Float16* w1 = WN1T + (size_t)(32 + ln31 ) * 192 + grp*8;
        const _Float16* w2 = WN1T + (size_t)(64 + ln31 ) * 192 + grp*8;
        const _Float16* w3 = WN1T + (size_t)(96 + ln31 ) * 192 + grp*8;
        #pragma unroll
        for (int ks = 0; ks < 12; ++ks){
            const unsigned int o = ((unsigned int)(ks*8 + grp*4)) ^ sA;
            f16x8 af = ldfrag4(Act, aRow + o);
            a0 = __builtin_amdgcn_mfma_f32_32x32x16_f16(af, ldg8h(w0 + ks*16), a0, 0, 0, 0);
            a1 = __builtin_amdgcn_mfma_f32_32x32x16_f16(af, ldg8h(w1 + ks*16), a1, 0, 0, 0);
            a2 = __builtin_amdgcn_mfma_f32_32x32x16_f16(af, ldg8h(w2 + ks*16), a2, 0, 0, 0);
            a3 = __builtin_amdgcn_mfma_f32_32x32x16_f16(af, ldg8h(w3 + ks*16), a3, 0, 0, 0);
        }
    }
    __syncthreads();
    // selu + writeback into own rows
    #pragma unroll
    for (int reg = 0; reg < 16; ++reg){
        int row = ROW_OF(reg);
        #pragma unroll
        for (int t = 0; t < 4; ++t){
            int col = t*32 + ln31;
            float v = (t==0) ? a0[reg] : (t==1) ? a1[reg] : (t==2) ? a2[reg] : a3[reg];
            unsigned int d = SWZ(row, col >> 1);
            acth[row*192 + (d << 1) + (col & 1)] = (_Float16)selu_f(v);
        }
    }
    __syncthreads();

    // ---- layer n2: K=128 ----
    {
        float bz0 = b_n2[ln31],    bz1 = b_n2[32+ln31];
        float bz2 = b_n2[64+ln31], bz3 = b_n2[96+ln31];
        #pragma unroll
        for (int reg = 0; reg < 16; ++reg){ a0[reg]=bz0; a1[reg]=bz1; a2[reg]=bz2; a3[reg]=bz3; }
        const _Float16* w0 = WN2T + (size_t)(ln31      ) * 128 + grp*8;
        const _Float16* w1 = WN2T + (size_t)(32 + ln31 ) * 128 + grp*8;
        const _Float16* w2 = WN2T + (size_t)(64 + ln31 ) * 128 + grp*8;
        const _Float16* w3 = WN2T + (size_t)(96 + ln31 ) * 128 + grp*8;
        #pragma unroll
        for (int ks = 0; ks < 8; ++ks){
            const unsigned int o = ((unsigned int)(ks*8 + grp*4)) ^ sA;
            f16x8 af = ldfrag4(Act, aRow + o);
            a0 = __builtin_amdgcn_mfma_f32_32x32x16_f16(af, ldg8h(w0 + ks*16), a0, 0, 0, 0);
            a1 = __builtin_amdgcn_mfma_f32_32x32x16_f16(af, ldg8h(w1 + ks*16), a1, 0, 0, 0);
            a2 = __builtin_amdgcn_mfma_f32_32x32x16_f16(af, ldg8h(w2 + ks*16), a2, 0, 0, 0);
            a3 = __builtin_amdgcn_mfma_f32_32x32x16_f16(af, ldg8h(w3 + ks*16), a3, 0, 0, 0);
        }
    }
    // ---- write out ----
    #pragma unroll
    for (int reg = 0; reg < 16; ++reg){
        int row = ROW_OF(reg);
        int node = g0 + row;
        if (node < n){
            float* op = out + (size_t)node * HDIM;
            op[ln31]      = a0[reg];
            op[32 + ln31] = a1[reg];
            op[64 + ln31] = a2[reg];
            op[96 + ln31] = a3[reg];
        }
    }
    #undef ROW_OF
}

extern "C" void kernel_launch(void* const* d_in, const int* in_sizes, int n_in,
                              void* d_out, int out_size, void* d_ws, size_t ws_size,
                              hipStream_t stream)
{
    const float* h          = (const float*)d_in[0];
    const float* coords     = (const float*)d_in[1];
    const int*   row_splits = (const int*)  d_in[2];
    const float* W_e1 = (const float*)d_in[3];
    const float* b_e1 = (const float*)d_in[4];
    const float* W_e2 = (const float*)d_in[5];
    const float* b_e2 = (const float*)d_in[6];
    const float* W_c1 = (const float*)d_in[7];
    const float* b_c1 = (const float*)d_in[8];
    const float* W_c2 = (const float*)d_in[9];
    const float* b_c2 = (const float*)d_in[10];
    const float* W_n1 = (const float*)d_in[11];
    const float* b_n1 = (const float*)d_in[12];
    const float* W_n2 = (const float*)d_in[13];
    const float* b_n2 = (const float*)d_in[14];

    const int n    = in_sizes[0] / FDIM;
    const int nseg = in_sizes[2] - 1;
    const int npad = n + PADN;

    float* out        = (float*)d_out;
    float* out_coords = out + (size_t)n * HDIM;
    float* out_nidx   = out_coords + (size_t)n * 3;
    float* out_d      = out_nidx + (size_t)n * KNB;

    int*          nidx_i = (int*)d_ws;
    float*        ndist  = (float*)(nidx_i + (size_t)n * KNB);
    int*          idx0   = (int*)(ndist + (size_t)n * KNB);
    _Float16*     WT     = (_Float16*)(idx0 + (size_t)n);     // 3 x 128x128 f16
    _Float16*     WN1T   = WT + 3 * 16384;                    // 128x192 f16
    _Float16*     WN2T   = WN1T + 128 * 192;                  // 128x128 f16
    unsigned int* aggbuf = (unsigned int*)(WN2T + 128 * 128); // n x 96 dwords
    float4*       c4     = (float4*)(aggbuf + (size_t)n * 96);// npad x float4

    const int prep_blocks = 352 + (npad + 255) / 256;
    prep_kernel<<<prep_blocks, 256, 0, stream>>>(W_e1, W_e2, W_c1, WT,
                                                 W_n1, WN1T, W_n2, WN2T,
                                                 coords, c4, n, npad);

    knn_kernel<<<n, 64, 0, stream>>>(c4, row_splits, nseg, n,
                                     nidx_i, ndist, idx0, out_nidx, out_d);

    egcn_node_kernel<<<(n + NPB - 1) / NPB, 256, 0, stream>>>(
        h, coords, nidx_i, ndist, idx0, WT,
        W_e1, b_e1, b_e2, b_c1, W_c2, b_c2,
        aggbuf, out_coords, n);

    node_mlp_kernel<<<(n + 127) / 128, 256, 0, stream>>>(
        aggbuf, WN1T, b_n1, WN2T, b_n2, out, n);
}

// Round 17
// 237.800 us; speedup vs baseline: 1.0389x; 1.0335x over previous
//
#include <hip/hip_runtime.h>
#include <cstdint>

#define KNB 16
#define FDIM 64
#define HDIM 128
#define NPB 8           // nodes per egcn block
#define ROWS 128        // edge rows per egcn block
#define CMAXW 80        // candidates per lane (segments up to 5120)
#define PADN 5120       // c4 padding entries

typedef unsigned long long ull;
typedef _Float16 f16x8 __attribute__((ext_vector_type(8)));
typedef float    f32x16 __attribute__((ext_vector_type(16)));

__device__ __forceinline__ float selu_f(float x){
    const float a = 1.6732632423543772f, s = 1.0507009873554805f;
    return x > 0.f ? s * x : s * a * (__expf(x) - 1.0f);
}

__device__ __forceinline__ unsigned int pack2(float a, float b){
    union { _Float16 h[2]; unsigned int u; } t;
    t.h[0] = (_Float16)a; t.h[1] = (_Float16)b;
    return t.u;
}

__device__ __forceinline__ f16x8 ldfrag4(const unsigned int* p, unsigned int di){
    union { uint4 q; f16x8 v; } t;
    t.q = *(const uint4*)(p + di);
    return t.v;
}

__device__ __forceinline__ f16x8 ldg8h(const _Float16* p){
    union { uint4 q; f16x8 v; } t;
    t.q = *(const uint4*)p;
    return t.v;
}

// ---- u32 min-reduce across a wave64 in pure-VALU DPP ----
template<int CTRL>
__device__ __forceinline__ unsigned int dppmin_u32(unsigned int v){
    unsigned int t = (unsigned int)__builtin_amdgcn_update_dpp(
        -1, (int)v, CTRL, 0xF, 0xF, false);
    return t < v ? t : v;
}
__device__ __forceinline__ unsigned int wave_min_u32(unsigned int v){
    v = dppmin_u32<0x111>(v);
    v = dppmin_u32<0x112>(v);
    v = dppmin_u32<0x114>(v);
    v = dppmin_u32<0x118>(v);
    v = dppmin_u32<0x142>(v);
    v = dppmin_u32<0x143>(v);
    return (unsigned int)__builtin_amdgcn_readlane((int)v, 63);
}

#define SWZ(row, d) ((unsigned int)(d) ^ ((((unsigned int)(row)) & 7u) << 2))

// ---------------------------------------------------------------------------
// Kernel 0: fused prep.
//  b in [0,192):   WT[n][k]   = W_e*[k][n] fp16 (3 x 128x128)
//  b in [192,288): WN1T[n][k] = W_n1[k][n] fp16 (128x192)
//  b in [288,352): WN2T[n][k] = W_n2[k][n] fp16 (128x128)
//  b >= 352:       c4[j] = {x,y,z,nrm}; pad = {0,0,0,+inf}
// ---------------------------------------------------------------------------
__global__ __launch_bounds__(256) void prep_kernel(
    const float* __restrict__ We1, const float* __restrict__ We2,
    const float* __restrict__ Wc1, _Float16* __restrict__ WT,
    const float* __restrict__ Wn1, _Float16* __restrict__ WN1T,
    const float* __restrict__ Wn2, _Float16* __restrict__ WN2T,
    const float* __restrict__ coords, float4* __restrict__ c4, int n, int npad)
{
    int b = blockIdx.x;
    if (b < 192){
        int id = b * 256 + threadIdx.x;
        int m  = id >> 14;
        int r  = id & 16383;
        int nn = (r >> 7) & 127;
        int k  = r & 127;
        float v;
        if (m == 0)      v = We1[(k + 1) * 128 + nn];
        else if (m == 1) v = We2[k * 128 + nn];
        else             v = Wc1[k * 128 + nn];
        WT[m * 16384 + nn * 128 + k] = (_Float16)v;
    } else if (b < 288){
        int id = (b - 192) * 256 + threadIdx.x;   // 0..24575
        int nn = id / 192, k = id - nn * 192;
        WN1T[nn * 192 + k] = (_Float16)Wn1[k * 128 + nn];
    } else if (b < 352){
        int id = (b - 288) * 256 + threadIdx.x;   // 0..16383
        int nn = id >> 7, k = id & 127;
        WN2T[nn * 128 + k] = (_Float16)Wn2[k * 128 + nn];
    } else {
        int i = (b - 352) * 256 + threadIdx.x;
        if (i < n){
            float x = coords[3*i], y = coords[3*i+1], z = coords[3*i+2];
            float nrm = __fadd_rn(__fadd_rn(__fmul_rn(x,x), __fmul_rn(y,y)), __fmul_rn(z,z));
            c4[i] = make_float4(x, y, z, nrm);
        } else if (i < npad){
            c4[i] = make_float4(0.f, 0.f, 0.f, __uint_as_float(0x7f800000u));
        }
    }
}

// ---------------------------------------------------------------------------
// Kernel 1: exact KNN, one wave per block (grid = n). R14 config — the
// empirical best. Serial u64 top-3 insert chain is this algorithm's floor
// (R13 dual-chain and R15 manual pipeline both defeated by regalloc).
// ---------------------------------------------------------------------------
__global__ __launch_bounds__(64) void knn_kernel(
    const float4* __restrict__ c4,
    const int* __restrict__ row_splits, int nseg, int n,
    int* __restrict__ nidx, float* __restrict__ ndist, int* __restrict__ idx0,
    float* __restrict__ out_nidx, float* __restrict__ out_d)
{
    const int lane = threadIdx.x;
    const int i    = blockIdx.x;
    if (i >= n) return;

    int lo = 0, hi = n;
    for (int s = 0; s < nseg; ++s){
        int a = row_splits[s], b = row_splits[s+1];
        if (i >= a && i < b){ lo = a; hi = b; }
    }

    const float4 ci = c4[i];
    const float cx = ci.x, cy = ci.y, cz = ci.z, nrmi = ci.w;

    const int jbase = lo + lane;
    const float FINF = __uint_as_float(0x7f800000u);

    ull m1 = ~0ull, m2 = ~0ull, m3 = ~0ull;

    #define D2_OF(v) __fsub_rn(__fadd_rn(nrmi, (v).w), __fmul_rn(2.0f, \
        __fadd_rn(__fadd_rn(__fmul_rn(cx,(v).x), __fmul_rn(cy,(v).y)), __fmul_rn(cz,(v).z))))
    #define INS(kk) { \
        ull n1 = (kk) < m1 ? (kk) : m1; \
        ull t1 = (kk) < m1 ? m1 : (kk); \
        ull n2 = t1 < m2 ? t1 : m2; \
        ull t2 = t1 < m2 ? m2 : t1; \
        ull n3 = t2 < m3 ? t2 : m3; \
        m1 = n1; m2 = n2; m3 = n3; }

    for (int c0 = 0; c0 < CMAXW; c0 += 8){
        float4 v[8]; int jj[8];
        #pragma unroll
        for (int q = 0; q < 8; ++q){
            jj[q] = jbase + (c0 + q)*64;
            v[q]  = c4[jj[q]];            // pad region returns {0,0,0,inf}
        }
        #pragma unroll
        for (int q = 0; q < 8; ++q){
            float dv = (jj[q] < hi) ? fmaxf(D2_OF(v[q]), 0.0f) : FINF;
            ull kk = (((ull)__float_as_uint(dv)) << 32) | (unsigned int)jj[q];
            INS(kk)
        }
    }
    int vcnt = 3;

    for (int r = 0; r < KNB + 1; ++r){
        unsigned int h32 = (unsigned int)(m1 >> 32);
        unsigned int l32 = (unsigned int)m1;
        unsigned int wmd = wave_min_u32(h32);
        unsigned int jm  = (h32 == wmd) ? l32 : 0xFFFFFFFFu;
        unsigned int wmj = wave_min_u32(jm);

        bool own = (h32 == wmd) && (l32 == wmj);
        bool need = false;
        if (own){
            int   j  = (int)wmj;
            float dv = __uint_as_float(wmd);
            if (r == 0){
                idx0[i] = j;
            } else {
                int rr = r - 1;
                nidx[i*KNB + rr]     = j;
                ndist[i*KNB + rr]    = dv;
                out_nidx[i*KNB + rr] = (float)j;
                out_d[i*KNB + rr]    = dv;
            }
            m1 = m2; m2 = m3; m3 = ~0ull;
            need = (--vcnt == 0);
        }

        if (__ballot((int)need)){   // wave-uniform: body never issues if untaken
            if (need){
                ull b = (((ull)wmd) << 32) | wmj;
                m1 = m2 = m3 = ~0ull;
                for (int c = 0; c < CMAXW; ++c){
                    int j = jbase + c*64;
                    float4 v = c4[j];
                    float dv = (j < hi) ? fmaxf(D2_OF(v), 0.0f) : FINF;
                    ull kk = (((ull)__float_as_uint(dv)) << 32) | (unsigned int)j;
                    kk = kk > b ? kk : ~0ull;
                    INS(kk)
                }
                vcnt = 3;
            }
        }
    }
    #undef INS
    #undef D2_OF
}

// ---------------------------------------------------------------------------
// Kernel 2: egcn, R10 structure (LDS wt staging, XOR swizzle, (256,2) — the
// no-spill config). aggbuf written as fp16 for the MFMA node MLP.
// (unchanged this round)
// ---------------------------------------------------------------------------
__global__ __launch_bounds__(256, 2) void egcn_node_kernel(
    const float* __restrict__ h, const float* __restrict__ coords,
    const int* __restrict__ nidx, const float* __restrict__ ndist,
    const int* __restrict__ idx0, const _Float16* __restrict__ WTg,
    const float* __restrict__ W_e1, const float* __restrict__ b_e1,
    const float* __restrict__ b_e2, const float* __restrict__ b_c1,
    const float* __restrict__ W_c2, const float* __restrict__ b_c2,
    unsigned int* __restrict__ aggout, float* __restrict__ out_coords, int n)
{
    __shared__ __attribute__((aligned(16))) _Float16 Act[ROWS * 128];   // 32768 B
    __shared__ __attribute__((aligned(16))) unsigned int wt[ROWS * 64]; // 32768 B
    __shared__ float agg[NPB][HDIM];                                    // 4096 B
    __shared__ float dls[ROWS];
    __shared__ int   nb[ROWS];
    __shared__ int   j0s[NPB];
    __shared__ float wedge[ROWS];

    const int g0  = blockIdx.x * NPB;
    const int tid = threadIdx.x;
    const int lane = tid & 63, wid = tid >> 6;
    const int ln31 = lane & 31, grp = lane >> 5;
    const int rt  = wid;                 // row tile 0..3 (32 edge rows each)

    if (tid < ROWS){
        int e = min(g0*KNB + tid, n*KNB - 1);
        nb[tid]  = nidx[e];
        dls[tid] = ndist[e];
    }
    if (tid < NPB) j0s[tid] = idx0[min(g0 + tid, n - 1)];
    __syncthreads();

    unsigned int* actd = (unsigned int*)Act;

    // ---- stage Act = [h_self | h_neig] fp16, float4 loads + swizzled b128 ----
    {
        int r = tid >> 1, half = tid & 1;
        const float4* hs = (const float4*)(h + (size_t)j0s[r >> 4] * FDIM + half*32);
        const float4* hn = (const float4*)(h + (size_t)nb[r] * FDIM + half*32);
        unsigned int rb = (unsigned int)r * 64;
        uint4 buf[4];
        #pragma unroll
        for (int q = 0; q < 4; ++q){
            float4 a = hs[2*q], b = hs[2*q+1];
            buf[q].x = pack2(a.x,a.y); buf[q].y = pack2(a.z,a.w);
            buf[q].z = pack2(b.x,b.y); buf[q].w = pack2(b.z,b.w);
        }
        #pragma unroll
        for (int q = 0; q < 4; ++q)
            *(uint4*)(actd + rb + SWZ(r, half*16 + 4*q)) = buf[q];
        #pragma unroll
        for (int q = 0; q < 4; ++q){
            float4 a = hn[2*q], b = hn[2*q+1];
            buf[q].x = pack2(a.x,a.y); buf[q].y = pack2(a.z,a.w);
            buf[q].z = pack2(b.x,b.y); buf[q].w = pack2(b.z,b.w);
        }
        #pragma unroll
        for (int q = 0; q < 4; ++q)
            *(uint4*)(actd + rb + SWZ(r, 32 + half*16 + 4*q)) = buf[q];
    }
    auto stage_wt = [&](const _Float16* Wg){
        int nr = tid >> 1, half = tid & 1;
        const uint4* src = (const uint4*)(Wg + nr * 128 + half*64);
        unsigned int rb = (unsigned int)nr * 64;
        #pragma unroll
        for (int q = 0; q < 8; ++q)
            *(uint4*)(wt + rb + SWZ(nr, half*32 + q*4)) = src[q];
    };
    stage_wt(WTg);
    __syncthreads();

    const unsigned int sA    = ((unsigned int)ln31 & 7u) << 2;
    const unsigned int aRow  = (unsigned int)(rt*32 + ln31) * 64;
    const unsigned int bRow0 = (unsigned int)(ln31      ) * 64;
    const unsigned int bRow1 = (unsigned int)(32  + ln31) * 64;
    const unsigned int bRow2 = (unsigned int)(64  + ln31) * 64;
    const unsigned int bRow3 = (unsigned int)(96  + ln31) * 64;

    auto gemm4 = [&](f32x16& A0, f32x16& A1, f32x16& A2, f32x16& A3){
        #pragma unroll
        for (int ks = 0; ks < 8; ++ks){
            const unsigned int o = ((unsigned int)(ks*8 + grp*4)) ^ sA;
            f16x8 af = ldfrag4(actd, aRow + o);
            A0 = __builtin_amdgcn_mfma_f32_32x32x16_f16(af, ldfrag4(wt, bRow0 + o), A0, 0, 0, 0);
            A1 = __builtin_amdgcn_mfma_f32_32x32x16_f16(af, ldfrag4(wt, bRow1 + o), A1, 0, 0, 0);
            A2 = __builtin_amdgcn_mfma_f32_32x32x16_f16(af, ldfrag4(wt, bRow2 + o), A2, 0, 0, 0);
            A3 = __builtin_amdgcn_mfma_f32_32x32x16_f16(af, ldfrag4(wt, bRow3 + o), A3, 0, 0, 0);
        }
    };
    #define ROW_OF(reg) (rt*32 + ((reg)&3) + 8*((reg)>>2) + 4*grp)

    auto act_st = [&](int row, int col, float v){
        unsigned int d = SWZ(row, col >> 1);
        Act[row*128 + (d << 1) + (col & 1)] = (_Float16)v;
    };

    // ================= layer e1 (129 -> 128) =================
    {
        float w00 = W_e1[ln31],      w01 = W_e1[32+ln31];
        float w02 = W_e1[64+ln31],   w03 = W_e1[96+ln31];
        float bz0 = b_e1[ln31],      bz1 = b_e1[32+ln31];
        float bz2 = b_e1[64+ln31],   bz3 = b_e1[96+ln31];
        f32x16 a0, a1, a2, a3;
        #pragma unroll
        for (int reg = 0; reg < 16; ++reg){
            float dv = dls[ROW_OF(reg)];
            a0[reg] = fmaf(dv, w00, bz0);
            a1[reg] = fmaf(dv, w01, bz1);
            a2[reg] = fmaf(dv, w02, bz2);
            a3[reg] = fmaf(dv, w03, bz3);
        }
        gemm4(a0, a1, a2, a3);
        __syncthreads();
        #pragma unroll
        for (int reg = 0; reg < 16; ++reg){
            int row = ROW_OF(reg);
            act_st(row, ln31,      selu_f(a0[reg]));
            act_st(row, 32 + ln31, selu_f(a1[reg]));
            act_st(row, 64 + ln31, selu_f(a2[reg]));
            act_st(row, 96 + ln31, selu_f(a3[reg]));
        }
        stage_wt(WTg + 16384);
        __syncthreads();
    }

    // ================= layer e2 (128 -> 128), e_sum fused =================
    {
        float bz0 = b_e2[ln31],    bz1 = b_e2[32+ln31];
        float bz2 = b_e2[64+ln31], bz3 = b_e2[96+ln31];
        f32x16 a0, a1, a2, a3;
        #pragma unroll
        for (int reg = 0; reg < 16; ++reg){ a0[reg]=bz0; a1[reg]=bz1; a2[reg]=bz2; a3[reg]=bz3; }
        gemm4(a0, a1, a2, a3);
        __syncthreads();
        float e0[16], e1v[16], e2v[16], e3[16];
        float sl0=0.f, sh0=0.f, sl1=0.f, sh1=0.f, sl2=0.f, sh2=0.f, sl3=0.f, sh3=0.f;
        #pragma unroll
        for (int reg = 0; reg < 16; ++reg){
            e0[reg]=selu_f(a0[reg]); e1v[reg]=selu_f(a1[reg]);
            e2v[reg]=selu_f(a2[reg]); e3[reg]=selu_f(a3[reg]);
            if (reg < 8){ sl0+=e0[reg]; sl1+=e1v[reg]; sl2+=e2v[reg]; sl3+=e3[reg]; }
            else        { sh0+=e0[reg]; sh1+=e1v[reg]; sh2+=e2v[reg]; sh3+=e3[reg]; }
        }
        sl0 += __shfl_xor(sl0, 32, 64);  sh0 += __shfl_xor(sh0, 32, 64);
        sl1 += __shfl_xor(sl1, 32, 64);  sh1 += __shfl_xor(sh1, 32, 64);
        sl2 += __shfl_xor(sl2, 32, 64);  sh2 += __shfl_xor(sh2, 32, 64);
        sl3 += __shfl_xor(sl3, 32, 64);  sh3 += __shfl_xor(sh3, 32, 64);
        if (grp == 0){
            agg[rt*2+0][ln31]      = sl0;  agg[rt*2+1][ln31]      = sh0;
            agg[rt*2+0][32 + ln31] = sl1;  agg[rt*2+1][32 + ln31] = sh1;
            agg[rt*2+0][64 + ln31] = sl2;  agg[rt*2+1][64 + ln31] = sh2;
            agg[rt*2+0][96 + ln31] = sl3;  agg[rt*2+1][96 + ln31] = sh3;
        }
        #pragma unroll
        for (int reg = 0; reg < 16; ++reg){
            int row = ROW_OF(reg);
            act_st(row, ln31,      e0[reg]);
            act_st(row, 32 + ln31, e1v[reg]);
            act_st(row, 64 + ln31, e2v[reg]);
            act_st(row, 96 + ln31, e3[reg]);
        }
        stage_wt(WTg + 2*16384);
        __syncthreads();
    }

    // ================= layer c1 (128 -> 128) + c2 fused =================
    {
        float bz0 = b_c1[ln31],    bz1 = b_c1[32+ln31];
        float bz2 = b_c1[64+ln31], bz3 = b_c1[96+ln31];
        f32x16 a0, a1, a2, a3;
        #pragma unroll
        for (int reg = 0; reg < 16; ++reg){ a0[reg]=bz0; a1[reg]=bz1; a2[reg]=bz2; a3[reg]=bz3; }
        gemm4(a0, a1, a2, a3);
        __syncthreads();
        float wc0 = W_c2[ln31],    wc1 = W_c2[32+ln31];
        float wc2 = W_c2[64+ln31], wc3 = W_c2[96+ln31];
        float bc2 = b_c2[0];
        float p[16];
        #pragma unroll
        for (int reg = 0; reg < 16; ++reg)
            p[reg] = selu_f(a0[reg])*wc0 + selu_f(a1[reg])*wc1
                   + selu_f(a2[reg])*wc2 + selu_f(a3[reg])*wc3;
        #pragma unroll
        for (int msk = 16; msk > 0; msk >>= 1){
            #pragma unroll
            for (int reg = 0; reg < 16; ++reg)
                p[reg] += __shfl_xor(p[reg], msk, 64);
        }
        if (ln31 == 0){
            #pragma unroll
            for (int reg = 0; reg < 16; ++reg)
                wedge[ROW_OF(reg)] = bc2 + p[reg];
        }
        __syncthreads();
    }

    // ================= epilogue: coords, fp16 agg writeback =================
    if (tid < 3*NPB){
        int nd = tid / 3, c = tid - nd*3;
        int gi = min(g0 + nd, n - 1);
        float ci = coords[3*gi + c];
        float s = 0.f;
        #pragma unroll
        for (int k = 0; k < KNB; ++k){
            int e = nd*KNB + k;
            s += (ci - coords[3*nb[e] + c]) * wedge[e];
        }
        if (g0 + nd < n) out_coords[3*gi + c] = ci + s * (1.0f/KNB);
    }

    for (int s = tid; s < NPB*96; s += 256){
        int nd = s / 96, c2 = s - nd*96;
        if (g0 + nd < n){
            int c = c2 * 2;
            float v0 = (c   < HDIM) ? agg[nd][c]
                                    : h[(size_t)j0s[nd]*FDIM + (c - HDIM)];
            float v1 = (c+1 < HDIM) ? agg[nd][c+1]
                                    : h[(size_t)j0s[nd]*FDIM + (c+1 - HDIM)];
            aggout[(size_t)(g0 + nd)*96 + c2] = pack2(v0, v1);
        }
    }
}

// ---------------------------------------------------------------------------
// Kernel 3: node MLP as MFMA — WAVE-LOCAL rewrite. R16 audit: old version
// ran 79 blocks on 256 CUs (>=69% of the machine idle) with two full-block
// barriers around global-latency MFMA chains. Now: 64-thread blocks, 32
// nodes each (313 blocks), each wave owns its rows end-to-end; LDS 12.3KB;
// __syncthreads in a 1-wave block is just a waitcnt.
// ---------------------------------------------------------------------------
__global__ __launch_bounds__(64) void node_mlp_kernel(
    const unsigned int* __restrict__ aggin,   // n rows x 96 dwords (192 f16)
    const _Float16* __restrict__ WN1T, const float* __restrict__ b_n1,
    const _Float16* __restrict__ WN2T, const float* __restrict__ b_n2,
    float* __restrict__ out, int n)
{
    __shared__ __attribute__((aligned(16))) unsigned int Act[32 * 96]; // 12288 B
    _Float16* acth = (_Float16*)Act;

    const int g0  = blockIdx.x * 32;
    const int tid = threadIdx.x;              // 0..63 (one wave)
    const int ln31 = tid & 31, grp = tid >> 5;

    // ---- stage 32 rows x 24 uint4 chunks, swizzled (12 chunks/lane) ----
    const int maxch = n * 24 - 1;
    #pragma unroll
    for (int q = 0; q < 12; ++q){
        int ch = q * 64 + tid;                // 0..767
        int r  = ch / 24, c = ch - r * 24;
        int gch = min(g0 * 24 + ch, maxch);
        uint4 v = *(const uint4*)(aggin + (size_t)gch * 4);
        *(uint4*)(Act + r * 96 + SWZ(r, 4 * c)) = v;
    }
    __syncthreads();                           // 1-wave block: waitcnt only

    const unsigned int sA   = ((unsigned int)ln31 & 7u) << 2;
    const unsigned int aRow = (unsigned int)ln31 * 96;
    #define ROW_OF(reg) (((reg)&3) + 8*((reg)>>2) + 4*grp)

    // ---- layer n1: K=192 ----
    f32x16 a0, a1, a2, a3;
    {
        float bz0 = b_n1[ln31],    bz1 = b_n1[32+ln31];
        float bz2 = b_n1[64+ln31], bz3 = b_n1[96+ln31];
        #pragma unroll
        for (int reg = 0; reg < 16; ++reg){ a0[reg]=bz0; a1[reg]=bz1; a2[reg]=bz2; a3[reg]=bz3; }
        const _Float16* w0 = WN1T + (size_t)(ln31      ) * 192 + grp*8;
        const _Float16* w1 = WN1T + (size_t)(32 + ln31 ) * 192 + grp*8;
        const _Float16* w2 = WN1T + (size_t)(64 + ln31 ) * 192 + grp*8;
        const _Float16* w3 = WN1T + (size_t)(96 + ln31 ) * 192 + grp*8;
        #pragma unroll
        for (int ks = 0; ks < 12; ++ks){
            const unsigned int o = ((unsigned int)(ks*8 + grp*4)) ^ sA;
            f16x8 af = ldfrag4(Act, aRow + o);
            a0 = __builtin_amdgcn_mfma_f32_32x32x16_f16(af, ldg8h(w0 + ks*16), a0, 0, 0, 0);
            a1 = __builtin_amdgcn_mfma_f32_32x32x16_f16(af, ldg8h(w1 + ks*16), a1, 0, 0, 0);
            a2 = __builtin_amdgcn_mfma_f32_32x32x16_f16(af, ldg8h(w2 + ks*16), a2, 0, 0, 0);
            a3 = __builtin_amdgcn_mfma_f32_32x32x16_f16(af, ldg8h(w3 + ks*16), a3, 0, 0, 0);
        }
    }
    __syncthreads();
    // selu + writeback into own rows (first 128 halves of each row)
    #pragma unroll
    for (int reg = 0; reg < 16; ++reg){
        int row = ROW_OF(reg);
        #pragma unroll
        for (int t = 0; t < 4; ++t){
            int col = t*32 + ln31;
            float v = (t==0) ? a0[reg] : (t==1) ? a1[reg] : (t==2) ? a2[reg] : a3[reg];
            unsigned int d = SWZ(row, col >> 1);
            acth[row*192 + (d << 1) + (col & 1)] = (_Float16)selu_f(v);
        }
    }
    __syncthreads();

    // ---- layer n2: K=128 ----
    {
        float bz0 = b_n2[ln31],    bz1 = b_n2[32+ln31];
        float bz2 = b_n2[64+ln31], bz3 = b_n2[96+ln31];
        #pragma unroll
        for (int reg = 0; reg < 16; ++reg){ a0[reg]=bz0; a1[reg]=bz1; a2[reg]=bz2; a3[reg]=bz3; }
        const _Float16* w0 = WN2T + (size_t)(ln31      ) * 128 + grp*8;
        const _Float16* w1 = WN2T + (size_t)(32 + ln31 ) * 128 + grp*8;
        const _Float16* w2 = WN2T + (size_t)(64 + ln31 ) * 128 + grp*8;
        const _Float16* w3 = WN2T + (size_t)(96 + ln31 ) * 128 + grp*8;
        #pragma unroll
        for (int ks = 0; ks < 8; ++ks){
            const unsigned int o = ((unsigned int)(ks*8 + grp*4)) ^ sA;
            f16x8 af = ldfrag4(Act, aRow + o);
            a0 = __builtin_amdgcn_mfma_f32_32x32x16_f16(af, ldg8h(w0 + ks*16), a0, 0, 0, 0);
            a1 = __builtin_amdgcn_mfma_f32_32x32x16_f16(af, ldg8h(w1 + ks*16), a1, 0, 0, 0);
            a2 = __builtin_amdgcn_mfma_f32_32x32x16_f16(af, ldg8h(w2 + ks*16), a2, 0, 0, 0);
            a3 = __builtin_amdgcn_mfma_f32_32x32x16_f16(af, ldg8h(w3 + ks*16), a3, 0, 0, 0);
        }
    }
    // ---- write out ----
    #pragma unroll
    for (int reg = 0; reg < 16; ++reg){
        int row = ROW_OF(reg);
        int node = g0 + row;
        if (node < n){
            float* op = out + (size_t)node * HDIM;
            op[ln31]      = a0[reg];
            op[32 + ln31] = a1[reg];
            op[64 + ln31] = a2[reg];
            op[96 + ln31] = a3[reg];
        }
    }
    #undef ROW_OF
}

extern "C" void kernel_launch(void* const* d_in, const int* in_sizes, int n_in,
                              void* d_out, int out_size, void* d_ws, size_t ws_size,
                              hipStream_t stream)
{
    const float* h          = (const float*)d_in[0];
    const float* coords     = (const float*)d_in[1];
    const int*   row_splits = (const int*)  d_in[2];
    const float* W_e1 = (const float*)d_in[3];
    const float* b_e1 = (const float*)d_in[4];
    const float* W_e2 = (const float*)d_in[5];
    const float* b_e2 = (const float*)d_in[6];
    const float* W_c1 = (const float*)d_in[7];
    const float* b_c1 = (const float*)d_in[8];
    const float* W_c2 = (const float*)d_in[9];
    const float* b_c2 = (const float*)d_in[10];
    const float* W_n1 = (const float*)d_in[11];
    const float* b_n1 = (const float*)d_in[12];
    const float* W_n2 = (const float*)d_in[13];
    const float* b_n2 = (const float*)d_in[14];

    const int n    = in_sizes[0] / FDIM;
    const int nseg = in_sizes[2] - 1;
    const int npad = n + PADN;

    float* out        = (float*)d_out;
    float* out_coords = out + (size_t)n * HDIM;
    float* out_nidx   = out_coords + (size_t)n * 3;
    float* out_d      = out_nidx + (size_t)n * KNB;

    int*          nidx_i = (int*)d_ws;
    float*        ndist  = (float*)(nidx_i + (size_t)n * KNB);
    int*          idx0   = (int*)(ndist + (size_t)n * KNB);
    _Float16*     WT     = (_Float16*)(idx0 + (size_t)n);     // 3 x 128x128 f16
    _Float16*     WN1T   = WT + 3 * 16384;                    // 128x192 f16
    _Float16*     WN2T   = WN1T + 128 * 192;                  // 128x128 f16
    unsigned int* aggbuf = (unsigned int*)(WN2T + 128 * 128); // n x 96 dwords
    float4*       c4     = (float4*)(aggbuf + (size_t)n * 96);// npad x float4

    const int prep_blocks = 352 + (npad + 255) / 256;
    prep_kernel<<<prep_blocks, 256, 0, stream>>>(W_e1, W_e2, W_c1, WT,
                                                 W_n1, WN1T, W_n2, WN2T,
                                                 coords, c4, n, npad);

    knn_kernel<<<n, 64, 0, stream>>>(c4, row_splits, nseg, n,
                                     nidx_i, ndist, idx0, out_nidx, out_d);

    egcn_node_kernel<<<(n + NPB - 1) / NPB, 256, 0, stream>>>(
        h, coords, nidx_i, ndist, idx0, WT,
        W_e1, b_e1, b_e2, b_c1, W_c2, b_c2,
        aggbuf, out_coords, n);

    node_mlp_kernel<<<(n + 31) / 32, 64, 0, stream>>>(
        aggbuf, WN1T, b_n1, WN2T, b_n2, out, n);
}